// Round 9
// baseline (317.968 us; speedup 1.0000x reference)
//
#include <hip/hip_runtime.h>
#include <hip/hip_bf16.h>
#include <stdint.h>

// Problem dims (fixed by reference)
#define HH 224
#define WW 224
#define CC 1024
#define BB 256
#define KK (HH*WW)            // 50176
#define EPSILON_F 0.001f
#define LOG2E 1.4426950408889634f
#define INVN (1.0f/50176.0f)
// clip(v,+-2000)/N == clip(v/N, +-2000/N) since 1/N > 0
#define CLAMP_V (2000.0f/50176.0f)

// HISTORY:
// R1: XCD swizzle (FETCH 200->13.6MB). R2: unroll restructure -2.7x, reverted.
// R3: fp32-direct thrashed L2, cvt prepass kept. R4: A-LDS round-trip deleted
// (A global->reg, MFMA-layout loads) -> 55.8us gemm, latency-bound.
// R5: thinner steps at 2x blocks REGRESSED (101us). R6: paired rounds, schedule
// bug -> wrong results. R7: fixed pairing 83.5us (issue-before-barrier = uncovered
// vmcnt drain). R8: issue-at-top 73.2us -- still worse than R4's plain loop.
// => R5+R8 refute the barrier-count theory. Gemm reverted to R4 permanently.
// R9 (this round): THE CONSTANT ~93us. Every round: total = gemm + ~93us
// (R0 63.4+94.9, R1 56.6+91.2, R4 55.8+93.8, R8 73.2+93.0). cvt+reduce busy is
// <20us of it -> the rest is 3-dispatch launch/serialization overhead. Fix: fuse
// cvt + gemm + reduce into ONE dispatch with hand-rolled grid syncs. 512 blocks
// <= guaranteed residency (VGPR->4/CU, LDS->8/CU capacity; need only 2/CU) so the
// soft barrier cannot deadlock. Counter in ws, memset per launch (graph-legal).
#define KCHUNKS 32
#define ROWS_PER_CHUNK 7
#define STEPS 49              // 7 wb * 7 rows

// 36 elems = 72 B rows: 16-row b128 bank starts (18*r)%32 all distinct -> <=2-way
#define LDS_STRIDE 36

#define NBLK 512
#define OCT_PER_BLK 3136      // n8 / NBLK = 1605632 / 512

typedef __bf16 bf16x8 __attribute__((ext_vector_type(8)));
typedef float  f32x4  __attribute__((ext_vector_type(4)));

// ---------------- standalone kernels (fallback paths) -------------------------------------
__global__ __launch_bounds__(256)
void cvt_bf16_kernel(const float* __restrict__ x, __hip_bfloat16* __restrict__ xb, int n8) {
    int i = blockIdx.x * 256 + threadIdx.x;   // one thread per 8 elements
    if (i >= n8) return;
    const float4* p = (const float4*)(x + (size_t)i * 8);
    float4 a = p[0], b = p[1];
    union { __hip_bfloat16 h[8]; uint4 u; } o;
    o.h[0] = (__hip_bfloat16)a.x; o.h[1] = (__hip_bfloat16)a.y;
    o.h[2] = (__hip_bfloat16)a.z; o.h[3] = (__hip_bfloat16)a.w;
    o.h[4] = (__hip_bfloat16)b.x; o.h[5] = (__hip_bfloat16)b.y;
    o.h[6] = (__hip_bfloat16)b.z; o.h[7] = (__hip_bfloat16)b.w;
    *(uint4*)(xb + (size_t)i * 8) = o.u;
}

__global__ __launch_bounds__(256)
void reduce_kernel(const float* __restrict__ part, float* __restrict__ out) {
    int i = blockIdx.x * 256 + threadIdx.x;          // 65536 float4 slots
    const f32x4* p = (const f32x4*)part + i;
    f32x4 s = {0.f, 0.f, 0.f, 0.f};
#pragma unroll
    for (int z = 0; z < KCHUNKS; ++z)
        s += p[(size_t)z * (BB * CC / 4)];
    ((f32x4*)out)[i] = s;
}

// ---------------- device-scope soft grid barrier ------------------------------------------
// Precondition: grid <= guaranteed-resident block count (512 here). Counter is
// monotonic within a launch (memset to 0 by kernel_launch each replay).
__device__ __forceinline__ void grid_sync(unsigned* cnt, unsigned target) {
    __syncthreads();
    if (threadIdx.x == 0) {
        __hip_atomic_fetch_add(cnt, 1u, __ATOMIC_RELEASE, __HIP_MEMORY_SCOPE_AGENT);
        while (__hip_atomic_load(cnt, __ATOMIC_ACQUIRE, __HIP_MEMORY_SCOPE_AGENT) < target) {
            __builtin_amdgcn_s_sleep(2);
        }
    }
    __syncthreads();
}

// ---------------- fused: cvt -> gemm -> reduce in one dispatch ----------------------------
__global__ __launch_bounds__(256)
void fused_blob_kernel(const float* __restrict__ x,
                       const float* __restrict__ pos,
                       const float* __restrict__ sig,
                       const float* __restrict__ cwt,
                       const float* __restrict__ xs,
                       const float* __restrict__ ys,
                       float* __restrict__ out,
                       __hip_bfloat16* __restrict__ xb,
                       float* __restrict__ part,
                       unsigned* __restrict__ cnt) {
    // B tile only (A goes global->register directly) -- R4 structure
    __shared__ __bf16 Bs[2][64 * LDS_STRIDE];    // 64 c-rows x 32 k
    __shared__ float  xrow[WW];
    __shared__ float  ycol[ROWS_PER_CHUNK];

    const int tid  = threadIdx.x;
    const int wave = tid >> 6;
    const int lane = tid & 63;

    // ================= PHASE A: cvt x -> xb (grid-strided slice) =================
    {
        const int base = blockIdx.x * OCT_PER_BLK;
#pragma unroll 1
        for (int i = tid; i < OCT_PER_BLK; i += 256) {
            const int o = base + i;
            const float4* p = (const float4*)(x + (size_t)o * 8);
            float4 a = p[0], b = p[1];
            union { __hip_bfloat16 h[8]; uint4 u; } ov;
            ov.h[0] = (__hip_bfloat16)a.x; ov.h[1] = (__hip_bfloat16)a.y;
            ov.h[2] = (__hip_bfloat16)a.z; ov.h[3] = (__hip_bfloat16)a.w;
            ov.h[4] = (__hip_bfloat16)b.x; ov.h[5] = (__hip_bfloat16)b.y;
            ov.h[6] = (__hip_bfloat16)b.z; ov.h[7] = (__hip_bfloat16)b.w;
            *(uint4*)(xb + (size_t)o * 8) = ov.u;
        }
    }
    grid_sync(cnt, NBLK);   // xb complete & visible device-wide

    // ================= PHASE B: R4 gemm (verbatim) -> partials ===================
    // ---- XCD-aware swizzle (bijective on 512): xcd = n&7 owns z in [4*xcd, 4*xcd+4) ----
    const int n  = blockIdx.x;
    const int j  = n >> 3;
    const int z  = (n & 7) * 4 + (j >> 4);             // K-chunk (32)
    const int c0 = (j & 15) * 64;                      // N-tile (16)
    const int k0 = z * (ROWS_PER_CHUNK * WW);

    if (tid < WW) xrow[tid] = xs[tid];                 // x_axis
    if (tid >= WW && tid < WW + ROWS_PER_CHUNK)
        ycol[tid - WW] = ys[(z * ROWS_PER_CHUNK + (tid - WW)) * WW];  // y_axis

    // ---- per-thread curve params: one c per thread, one k-octet ----
    const int q   = tid & 3;            // k-octet within 32-wide step
    const int cr0 = tid >> 2;           // 0..63: c-row
    const int c   = c0 + cr0;
    float A2, S2, P0, P1;
    {
        float s  = sig[c];
        float w  = cwt[c];
        float s2 = s * s;
        A2 = w / (6.283185307179586f * s2 + EPSILON_F) * INVN;
        S2 = LOG2E / (2.0f * s2 + EPSILON_F);
        P0 = pos[2 * c];
        P1 = pos[2 * c + 1];
    }
    // clamp is the identity unless some lane's |A2| can exceed CLAMP_V:
    // |v| = |A2| * Ex * ey with Ex,ey in (0,1]  -> wave-uniform skip, exact.
    const bool doClamp = __any(fabsf(A2) > CLAMP_V) != 0;

    const int bs_w = cr0 * LDS_STRIDE + q * 8;

    // wave m-quadrant: wave w covers m rows [64w, 64w+64), all 64 c
    const int wm = wave * 64;
    const int fl = lane & 15;
    const int fk = (lane >> 4) * 8;
    const int br_off = fl * LDS_STRIDE + fk;

    // ---- A fragment base pointers: global, MFMA layout (row wm+fl+16mi, k fk..fk+7) ----
    const __hip_bfloat16* afb[4];
#pragma unroll
    for (int mi = 0; mi < 4; ++mi)
        afb[mi] = xb + (size_t)(wm + fl + mi * 16) * KK + k0 + fk;

    f32x4 acc[4][4];
#pragma unroll
    for (int i = 0; i < 4; ++i)
#pragma unroll
        for (int jj = 0; jj < 4; ++jj) acc[i][jj] = (f32x4){0.f, 0.f, 0.f, 0.f};

    __syncthreads();   // axes ready

    // y-axis values into registers (7 broadcast LDS reads, once)
    float ycolr[ROWS_PER_CHUNK];
#pragma unroll
    for (int r = 0; r < ROWS_PER_CHUNK; ++r) ycolr[r] = ycol[r];

    // ---- step 0: A fragments direct from global; B generated into buffer 0 ----
    bf16x8 fa[4];
#pragma unroll
    for (int mi = 0; mi < 4; ++mi)
        fa[mi] = *(const bf16x8*)(afb[mi]);
    float Ex[8];
    {
        float4 xv0 = *(const float4*)(xrow + q * 8);
        float4 xv1 = *(const float4*)(xrow + q * 8 + 4);
        float xv[8] = {xv0.x, xv0.y, xv0.z, xv0.w, xv1.x, xv1.y, xv1.z, xv1.w};
#pragma unroll
        for (int i = 0; i < 8; ++i) {
            float dx = xv[i] - P1;
            Ex[i] = __builtin_amdgcn_exp2f(-(dx * S2 * dx));
        }
        float dy  = ycolr[0] - P0;
        float eyA = __builtin_amdgcn_exp2f(-(dy * S2 * dy)) * A2;
        float v[8];
#pragma unroll
        for (int i = 0; i < 8; ++i) v[i] = Ex[i] * eyA;
        if (doClamp) {
#pragma unroll
            for (int i = 0; i < 8; ++i) v[i] = fminf(fmaxf(v[i], -CLAMP_V), CLAMP_V);
        }
        union { __bf16 h[8]; uint4 u; } cv;
#pragma unroll
        for (int i = 0; i < 8; ++i) cv.h[i] = (__bf16)v[i];
        *(uint4*)(&Bs[0][bs_w]) = cv.u;
    }
    __syncthreads();   // buffer 0 ready

    // ---- main loop: step s computes on Bs[s&1]; stages B(s+1) into Bs[(s&1)^1];
    //      A(s+1) prefetched global->reg during s. 1 barrier/step. ----
    int nr = 1, nwb = 0;   // (row, wb) of the step being staged (s+1)
#pragma unroll 2
    for (int s = 0; s < STEPS; ++s) {
        const int cb = s & 1;

        // 1. prefetch next A fragments (longest latency first)
        uint4 pa[4];
        if (s < STEPS - 1) {
            const int koff = nr * WW + nwb * 32;   // wave-uniform
#pragma unroll
            for (int mi = 0; mi < 4; ++mi) pa[mi] = *(const uint4*)(afb[mi] + koff);
        }

        // 2. B fragments from current buffer
        bf16x8 fb[4];
#pragma unroll
        for (int i = 0; i < 4; ++i)
            fb[i] = *(const bf16x8*)(&Bs[cb][br_off + i * 16 * LDS_STRIDE]);

        // 3. generate B for step s+1 into the other buffer (overlaps ds_read latency)
        if (s < STEPS - 1) {
            if (nr == 0) {   // new wb: refresh Ex (wave-uniform branch)
                float4 xv0 = *(const float4*)(xrow + nwb * 32 + q * 8);
                float4 xv1 = *(const float4*)(xrow + nwb * 32 + q * 8 + 4);
                float xv[8] = {xv0.x, xv0.y, xv0.z, xv0.w, xv1.x, xv1.y, xv1.z, xv1.w};
#pragma unroll
                for (int i = 0; i < 8; ++i) {
                    float dx = xv[i] - P1;
                    Ex[i] = __builtin_amdgcn_exp2f(-(dx * S2 * dx));
                }
            }
            float dy  = ycolr[nr] - P0;
            float eyA = __builtin_amdgcn_exp2f(-(dy * S2 * dy)) * A2;
            float v[8];
#pragma unroll
            for (int i = 0; i < 8; ++i) v[i] = Ex[i] * eyA;
            if (doClamp) {
#pragma unroll
                for (int i = 0; i < 8; ++i) v[i] = fminf(fmaxf(v[i], -CLAMP_V), CLAMP_V);
            }
            union { __bf16 h[8]; uint4 u; } cv;
#pragma unroll
            for (int i = 0; i < 8; ++i) cv.h[i] = (__bf16)v[i];
            *(uint4*)(&Bs[cb ^ 1][bs_w]) = cv.u;
            ++nr;
            if (nr == ROWS_PER_CHUNK) { nr = 0; ++nwb; }
        }

        // 4. 16 MFMAs (fa in registers, fb from LDS)
#pragma unroll
        for (int mi = 0; mi < 4; ++mi)
#pragma unroll
            for (int ni = 0; ni < 4; ++ni)
                acc[mi][ni] = __builtin_amdgcn_mfma_f32_16x16x32_bf16(
                    fa[mi], fb[ni], acc[mi][ni], 0, 0, 0);

        // 5. commit prefetched A as next step's fragments
        if (s < STEPS - 1) {
#pragma unroll
            for (int mi = 0; mi < 4; ++mi) {
                union { uint4 u; bf16x8 h; } t; t.u = pa[mi];
                fa[mi] = t.h;
            }
        }
        __syncthreads();
    }

    // ---- partial write: C/D layout col=lane&15, row=(lane>>4)*4+reg ----
    const int orow = (lane >> 4) * 4;
    float* base = part + (size_t)z * BB * CC;
#pragma unroll
    for (int mi = 0; mi < 4; ++mi) {
        int m = wm + mi * 16 + orow;
#pragma unroll
        for (int ni = 0; ni < 4; ++ni) {
            int cc = c0 + ni * 16 + fl;
#pragma unroll
            for (int v = 0; v < 4; ++v)
                base[(size_t)(m + v) * CC + cc] = acc[mi][ni][v];
        }
    }

    grid_sync(cnt, 2 * NBLK);   // partials complete & visible device-wide

    // ================= PHASE C: reduce partials -> out ===========================
    if (tid < 128) {
        const int slot = blockIdx.x * 128 + tid;       // 65536 float4 slots
        const f32x4* p = (const f32x4*)part + slot;
        f32x4 s = {0.f, 0.f, 0.f, 0.f};
#pragma unroll
        for (int zz = 0; zz < KCHUNKS; ++zz)
            s += p[(size_t)zz * (BB * CC / 4)];
        ((f32x4*)out)[slot] = s;
    }
}

// ---------------- main fused curve-gen + GEMM (fallback, R4) ------------------------------
template <bool BF16A, bool PARTIAL>
__global__ __launch_bounds__(256)
void blob_gemm_kernel(const void* __restrict__ xin,
                      const float* __restrict__ pos,
                      const float* __restrict__ sig,
                      const float* __restrict__ cwt,
                      const float* __restrict__ xs,
                      const float* __restrict__ ys,
                      float* __restrict__ dst) {
    __shared__ __bf16 Bs[2][64 * LDS_STRIDE];
    __shared__ float  xrow[WW];
    __shared__ float  ycol[ROWS_PER_CHUNK];

    const int tid  = threadIdx.x;
    const int wave = tid >> 6;
    const int lane = tid & 63;

    const int n  = blockIdx.x;
    const int j  = n >> 3;
    const int z  = (n & 7) * 4 + (j >> 4);
    const int c0 = (j & 15) * 64;
    const int k0 = z * (ROWS_PER_CHUNK * WW);

    if (tid < WW) xrow[tid] = xs[tid];
    if (tid >= WW && tid < WW + ROWS_PER_CHUNK)
        ycol[tid - WW] = ys[(z * ROWS_PER_CHUNK + (tid - WW)) * WW];

    const int q   = tid & 3;
    const int cr0 = tid >> 2;
    const int c   = c0 + cr0;
    float A2, S2, P0, P1;
    {
        float s  = sig[c];
        float w  = cwt[c];
        float s2 = s * s;
        A2 = w / (6.283185307179586f * s2 + EPSILON_F) * INVN;
        S2 = LOG2E / (2.0f * s2 + EPSILON_F);
        P0 = pos[2 * c];
        P1 = pos[2 * c + 1];
    }
    const bool doClamp = __any(fabsf(A2) > CLAMP_V) != 0;

    const int bs_w = cr0 * LDS_STRIDE + q * 8;
    const int wm = wave * 64;
    const int fl = lane & 15;
    const int fk = (lane >> 4) * 8;
    const int br_off = fl * LDS_STRIDE + fk;

    const __hip_bfloat16* afb[4];
    const float* aff[4];
#pragma unroll
    for (int mi = 0; mi < 4; ++mi) {
        size_t off = (size_t)(wm + fl + mi * 16) * KK + k0 + fk;
        afb[mi] = (const __hip_bfloat16*)xin + off;
        aff[mi] = (const float*)xin + off;
    }

    f32x4 acc[4][4];
#pragma unroll
    for (int i = 0; i < 4; ++i)
#pragma unroll
        for (int jj = 0; jj < 4; ++jj) acc[i][jj] = (f32x4){0.f, 0.f, 0.f, 0.f};

    __syncthreads();

    float ycolr[ROWS_PER_CHUNK];
#pragma unroll
    for (int r = 0; r < ROWS_PER_CHUNK; ++r) ycolr[r] = ycol[r];

    bf16x8 fa[4];
#pragma unroll
    for (int mi = 0; mi < 4; ++mi) {
        if (BF16A) {
            fa[mi] = *(const bf16x8*)(afb[mi]);
        } else {
            float4 f0 = *(const float4*)(aff[mi]);
            float4 f1 = *(const float4*)(aff[mi] + 4);
            bf16x8 t;
            t[0] = (__bf16)f0.x; t[1] = (__bf16)f0.y; t[2] = (__bf16)f0.z; t[3] = (__bf16)f0.w;
            t[4] = (__bf16)f1.x; t[5] = (__bf16)f1.y; t[6] = (__bf16)f1.z; t[7] = (__bf16)f1.w;
            fa[mi] = t;
        }
    }
    float Ex[8];
    {
        float4 xv0 = *(const float4*)(xrow + q * 8);
        float4 xv1 = *(const float4*)(xrow + q * 8 + 4);
        float xv[8] = {xv0.x, xv0.y, xv0.z, xv0.w, xv1.x, xv1.y, xv1.z, xv1.w};
#pragma unroll
        for (int i = 0; i < 8; ++i) {
            float dx = xv[i] - P1;
            Ex[i] = __builtin_amdgcn_exp2f(-(dx * S2 * dx));
        }
        float dy  = ycolr[0] - P0;
        float eyA = __builtin_amdgcn_exp2f(-(dy * S2 * dy)) * A2;
        float v[8];
#pragma unroll
        for (int i = 0; i < 8; ++i) v[i] = Ex[i] * eyA;
        if (doClamp) {
#pragma unroll
            for (int i = 0; i < 8; ++i) v[i] = fminf(fmaxf(v[i], -CLAMP_V), CLAMP_V);
        }
        union { __bf16 h[8]; uint4 u; } cv;
#pragma unroll
        for (int i = 0; i < 8; ++i) cv.h[i] = (__bf16)v[i];
        *(uint4*)(&Bs[0][bs_w]) = cv.u;
    }
    __syncthreads();

    int nr = 1, nwb = 0;
#pragma unroll 2
    for (int s = 0; s < STEPS; ++s) {
        const int cb = s & 1;
        uint4  pa[4];
        float4 pf0[4], pf1[4];
        if (s < STEPS - 1) {
            const int koff = nr * WW + nwb * 32;
            if (BF16A) {
#pragma unroll
                for (int mi = 0; mi < 4; ++mi) pa[mi] = *(const uint4*)(afb[mi] + koff);
            } else {
#pragma unroll
                for (int mi = 0; mi < 4; ++mi) {
                    pf0[mi] = *(const float4*)(aff[mi] + koff);
                    pf1[mi] = *(const float4*)(aff[mi] + koff + 4);
                }
            }
        }
        bf16x8 fb[4];
#pragma unroll
        for (int i = 0; i < 4; ++i)
            fb[i] = *(const bf16x8*)(&Bs[cb][br_off + i * 16 * LDS_STRIDE]);
        if (s < STEPS - 1) {
            if (nr == 0) {
                float4 xv0 = *(const float4*)(xrow + nwb * 32 + q * 8);
                float4 xv1 = *(const float4*)(xrow + nwb * 32 + q * 8 + 4);
                float xv[8] = {xv0.x, xv0.y, xv0.z, xv0.w, xv1.x, xv1.y, xv1.z, xv1.w};
#pragma unroll
                for (int i = 0; i < 8; ++i) {
                    float dx = xv[i] - P1;
                    Ex[i] = __builtin_amdgcn_exp2f(-(dx * S2 * dx));
                }
            }
            float dy  = ycolr[nr] - P0;
            float eyA = __builtin_amdgcn_exp2f(-(dy * S2 * dy)) * A2;
            float v[8];
#pragma unroll
            for (int i = 0; i < 8; ++i) v[i] = Ex[i] * eyA;
            if (doClamp) {
#pragma unroll
                for (int i = 0; i < 8; ++i) v[i] = fminf(fmaxf(v[i], -CLAMP_V), CLAMP_V);
            }
            union { __bf16 h[8]; uint4 u; } cv;
#pragma unroll
            for (int i = 0; i < 8; ++i) cv.h[i] = (__bf16)v[i];
            *(uint4*)(&Bs[cb ^ 1][bs_w]) = cv.u;
            ++nr;
            if (nr == ROWS_PER_CHUNK) { nr = 0; ++nwb; }
        }
#pragma unroll
        for (int mi = 0; mi < 4; ++mi)
#pragma unroll
            for (int ni = 0; ni < 4; ++ni)
                acc[mi][ni] = __builtin_amdgcn_mfma_f32_16x16x32_bf16(
                    fa[mi], fb[ni], acc[mi][ni], 0, 0, 0);
        if (s < STEPS - 1) {
            if (BF16A) {
#pragma unroll
                for (int mi = 0; mi < 4; ++mi) {
                    union { uint4 u; bf16x8 h; } t; t.u = pa[mi];
                    fa[mi] = t.h;
                }
            } else {
#pragma unroll
                for (int mi = 0; mi < 4; ++mi) {
                    bf16x8 t;
                    t[0] = (__bf16)pf0[mi].x; t[1] = (__bf16)pf0[mi].y;
                    t[2] = (__bf16)pf0[mi].z; t[3] = (__bf16)pf0[mi].w;
                    t[4] = (__bf16)pf1[mi].x; t[5] = (__bf16)pf1[mi].y;
                    t[6] = (__bf16)pf1[mi].z; t[7] = (__bf16)pf1[mi].w;
                    fa[mi] = t;
                }
            }
        }
        __syncthreads();
    }

    const int orow = (lane >> 4) * 4;
    float* base = PARTIAL ? (dst + (size_t)z * BB * CC) : dst;
#pragma unroll
    for (int mi = 0; mi < 4; ++mi) {
        int m = wm + mi * 16 + orow;
#pragma unroll
        for (int ni = 0; ni < 4; ++ni) {
            int cc = c0 + ni * 16 + fl;
#pragma unroll
            for (int v = 0; v < 4; ++v) {
                if (PARTIAL)
                    base[(size_t)(m + v) * CC + cc] = acc[mi][ni][v];
                else
                    atomicAdd(base + (size_t)(m + v) * CC + cc, acc[mi][ni][v]);
            }
        }
    }
}

extern "C" void kernel_launch(void* const* d_in, const int* in_sizes, int n_in,
                              void* d_out, int out_size, void* d_ws, size_t ws_size,
                              hipStream_t stream) {
    const float* x   = (const float*)d_in[0];
    const float* pos = (const float*)d_in[1];
    const float* sg  = (const float*)d_in[2];
    const float* cw  = (const float*)d_in[3];
    const float* xs  = (const float*)d_in[4];
    const float* ys  = (const float*)d_in[5];
    float* out = (float*)d_out;

    dim3 grid(NBLK);               // 512 blocks (flattened, XCD-swizzled in-kernel)
    const size_t nx   = (size_t)BB * KK;
    const size_t XB   = nx * sizeof(__hip_bfloat16);            // 25.7 MB
    const size_t PART = (size_t)KCHUNKS * BB * CC * 4;          // 33.6 MB
    const int n8 = (int)(nx / 8);

    if (ws_size >= XB + PART + 128) {
        // R9: single fused dispatch (cvt -> gemm -> reduce) with soft grid syncs.
        __hip_bfloat16* xb = (__hip_bfloat16*)d_ws;
        float* part = (float*)((char*)d_ws + XB);
        unsigned* cnt = (unsigned*)((char*)d_ws + XB + PART);
        hipMemsetAsync(cnt, 0, 128, stream);
        fused_blob_kernel<<<grid, 256, 0, stream>>>(x, pos, sg, cw, xs, ys, out, xb, part, cnt);
    } else if (ws_size >= XB + PART) {
        __hip_bfloat16* xb = (__hip_bfloat16*)d_ws;
        float* part = (float*)((char*)d_ws + XB);
        cvt_bf16_kernel<<<(n8 + 255) / 256, 256, 0, stream>>>(x, xb, n8);
        blob_gemm_kernel<true, true><<<grid, 256, 0, stream>>>(xb, pos, sg, cw, xs, ys, part);
        reduce_kernel<<<BB * CC / 4 / 256, 256, 0, stream>>>(part, out);
    } else if (ws_size >= PART) {
        float* part = (float*)d_ws;
        blob_gemm_kernel<false, true><<<grid, 256, 0, stream>>>(x, pos, sg, cw, xs, ys, part);
        reduce_kernel<<<BB * CC / 4 / 256, 256, 0, stream>>>(part, out);
    } else if (ws_size >= XB) {
        __hip_bfloat16* xb = (__hip_bfloat16*)d_ws;
        hipMemsetAsync(out, 0, (size_t)BB * CC * sizeof(float), stream);
        cvt_bf16_kernel<<<(n8 + 255) / 256, 256, 0, stream>>>(x, xb, n8);
        blob_gemm_kernel<true, false><<<grid, 256, 0, stream>>>(xb, pos, sg, cw, xs, ys, out);
    } else {
        hipMemsetAsync(out, 0, (size_t)BB * CC * sizeof(float), stream);
        blob_gemm_kernel<false, false><<<grid, 256, 0, stream>>>(x, pos, sg, cw, xs, ys, out);
    }
}